// Round 11
// baseline (447.209 us; speedup 1.0000x reference)
//
#include <hip/hip_runtime.h>
#include <hip/hip_fp16.h>
#include <math.h>

#define IN_DIM 256
#define OUT_DIM 64
#define BROWS 256             // nodes per bucket (pairs format)
#define GROWS 128             // rows per gather block (half bucket)
#define SC_THREADS 512
#define SC_EPB 16
#define SC_EDGES (SC_THREADS * SC_EPB)  // 8192 edges per scatter block (391 blocks - proven best)
#define BM 128                // gemm rows per block
#define KC2 64                // gemm k-chunk (fp16 MFMA version)
#define LDH 68                // padded fp16 leading dim (136 B = 17*8, b64-aligned)
#define CSR_CAP 5120          // LDS CSR capacity per half-bucket (mean 4092, sigma ~64)

typedef _Float16 f16x4 __attribute__((ext_vector_type(4)));
typedef float f32x4 __attribute__((ext_vector_type(4)));

// ---------------------------------------------------------------------------
// K1: dst-only multisplit with fixed-capacity segments + LDS-staged
// COALESCED writes + FUSED out_deg via global atomics.
// Round-11 change: the entire src-byte side (staging atomics + 8 KB stb +
// copy-out + the count_src kernel) is replaced by one fire-and-forget
// global atomicAdd per edge, issued in the load loop. The remaining ~4
// LDS ops/edge keep the LDS pipe busy while the TCC atomic pipe (400 KB
// L2-resident out_deg) runs concurrently. LDS 52 -> 38 KB.
// ---------------------------------------------------------------------------
__global__ void __launch_bounds__(SC_THREADS) scatter_pairs_kernel(
        const int* __restrict__ src, const int* __restrict__ dst,
        int* __restrict__ dcursor, int* __restrict__ out_deg,
        unsigned* __restrict__ pairs,
        int n_edges, int nb, int cap) {
    __shared__ int lhd[512];            // dst: per-bucket count (kept)
    __shared__ int lbd[512];            // dst: reserved global base
    __shared__ int lod[512];            // dst: staged offset -> staging cursor -> end
    __shared__ unsigned stp[SC_EDGES];  // staged pairs, 32 KB

    const int t = threadIdx.x;
    const int wave = t >> 6;
    const int lane = t & 63;

    lhd[t] = 0;
    __syncthreads();

    // ---- load edges into regs + dst-bucket counts + out_deg atomics
    const int base = blockIdx.x * SC_EDGES;
    int s[SC_EPB], d[SC_EPB];
    if (base + SC_EDGES <= n_edges) {
        const int4* s4 = (const int4*)(src + base);
        const int4* d4 = (const int4*)(dst + base);
        #pragma unroll
        for (int j = 0; j < SC_EPB / 4; ++j) {
            int4 a = s4[j * SC_THREADS + t];
            int4 c = d4[j * SC_THREADS + t];
            s[4*j+0] = a.x; s[4*j+1] = a.y; s[4*j+2] = a.z; s[4*j+3] = a.w;
            d[4*j+0] = c.x; d[4*j+1] = c.y; d[4*j+2] = c.z; d[4*j+3] = c.w;
        }
        #pragma unroll
        for (int i = 0; i < SC_EPB; ++i) {
            atomicAdd(&lhd[d[i] >> 8], 1);
            atomicAdd(&out_deg[s[i]], 1);   // fire-and-forget, TCC pipe
        }
    } else {
        #pragma unroll
        for (int i = 0; i < SC_EPB; ++i) {
            int e = base + i * SC_THREADS + t;
            if (e < n_edges) {
                s[i] = src[e];
                d[i] = dst[e];
                atomicAdd(&lhd[d[i] >> 8], 1);
                atomicAdd(&out_deg[s[i]], 1);
            } else {
                s[i] = -1; d[i] = 0;
            }
        }
    }
    __syncthreads();

    // ---- reserve global chunks (one atomic per (block,bucket))
    for (int i = t; i < nb; i += SC_THREADS) {
        int c = lhd[i];
        lbd[i] = c ? atomicAdd(&dcursor[i], c) : 0;
    }

    // ---- block-local exclusive scan over per-bucket counts
    {
        int vd = (t < nb) ? lhd[t] : 0;
        lod[t] = vd;
        __syncthreads();
        #pragma unroll
        for (int dd = 1; dd < 512; dd <<= 1) {
            int td = (t >= dd) ? lod[t - dd] : 0;
            __syncthreads();
            lod[t] += td;
            __syncthreads();
        }
        lod[t] -= vd;     // own-element: no hazard
    }
    __syncthreads();

    // ---- stage bucket-sorted into LDS (lod advances to run ends)
    #pragma unroll
    for (int i = 0; i < SC_EPB; ++i) {
        if (s[i] >= 0) {
            int bkt = d[i] >> 8;
            int pos = atomicAdd(&lod[bkt], 1);
            stp[pos] = ((unsigned)s[i] << 8) | (unsigned)(d[i] & 255);
        }
    }
    __syncthreads();

    // ---- coalesced copy-out: wave per bucket run
    for (int b2 = wave; b2 < nb; b2 += SC_THREADS / 64) {
        int cnt = lhd[b2];
        if (cnt) {
            int st = lod[b2] - cnt;           // run start in staging
            int gb = lbd[b2];                 // offset within bucket slot
            unsigned* gp = pairs + (size_t)b2 * cap;
            for (int j = lane; j < cnt; j += 64)
                if (gb + j < cap) gp[gb + j] = stp[st + j];
        }
    }
}

// ---------------------------------------------------------------------------
// K2: MFMA GEMM (round-8 version, unchanged). fp16 in, fp32 accumulate,
// operand-swapped so each lane's D = 4 consecutive output cols of one row.
// ---------------------------------------------------------------------------
__global__ void __launch_bounds__(256) gemm_kernel(
        const float* __restrict__ h, const float* __restrict__ W,
        const int* __restrict__ out_deg, __half* __restrict__ m, int n_nodes) {
    __shared__ _Float16 hs[BM * LDH];        // 128 x 68 fp16 = 17.4 KB
    __shared__ _Float16 Wt[OUT_DIM * LDH];   // 64 x 68 fp16 = 8.7 KB (transposed)

    const int t = threadIdx.x;
    const int wave = t >> 6;
    const int lane = t & 63;
    const int lg = lane >> 4;       // k-subgroup / D col-subgroup
    const int li = lane & 15;       // A-row (out col) / B-col (node row)
    const int rowBase = blockIdx.x * BM;

    f32x4 acc[2][4];
    #pragma unroll
    for (int rt = 0; rt < 2; ++rt)
        #pragma unroll
        for (int ct = 0; ct < 4; ++ct)
            acc[rt][ct] = (f32x4){0.f, 0.f, 0.f, 0.f};

    for (int kc = 0; kc < IN_DIM / KC2; ++kc) {
        __syncthreads();
        // ---- stage hs: 128 rows x 64 k, fp32 -> fp16 (float4 loads)
        #pragma unroll
        for (int i = 0; i < 8; ++i) {
            int idx = t + 256 * i;          // 2048 float4s
            int row = idx >> 4;             // 16 float4 per row
            int s4 = idx & 15;
            float4 v = make_float4(0.f, 0.f, 0.f, 0.f);
            if (rowBase + row < n_nodes)
                v = *(const float4*)(h + (size_t)(rowBase + row) * IN_DIM
                                     + kc * KC2 + s4 * 4);
            _Float16* dp = &hs[row * LDH + s4 * 4];
            dp[0] = (_Float16)v.x; dp[1] = (_Float16)v.y;
            dp[2] = (_Float16)v.z; dp[3] = (_Float16)v.w;
        }
        // ---- stage Wt transposed: Wt[n][k] = W[kc*64+k][n], fp32 -> fp16
        #pragma unroll
        for (int i = 0; i < 16; ++i) {
            int idx = t + 256 * i;          // 4096 elems
            int k = idx >> 6;
            int n = idx & 63;
            Wt[n * LDH + k] = (_Float16)W[(size_t)(kc * KC2 + k) * OUT_DIM + n];
        }
        __syncthreads();

        #pragma unroll
        for (int ks = 0; ks < KC2 / 16; ++ks) {
            const int k0 = ks * 16 + lg * 4;
            f16x4 b0 = *(const f16x4*)&hs[((wave * 2 + 0) * 16 + li) * LDH + k0];
            f16x4 b1 = *(const f16x4*)&hs[((wave * 2 + 1) * 16 + li) * LDH + k0];
            f16x4 a0 = *(const f16x4*)&Wt[(0 * 16 + li) * LDH + k0];
            f16x4 a1 = *(const f16x4*)&Wt[(1 * 16 + li) * LDH + k0];
            f16x4 a2 = *(const f16x4*)&Wt[(2 * 16 + li) * LDH + k0];
            f16x4 a3 = *(const f16x4*)&Wt[(3 * 16 + li) * LDH + k0];
            acc[0][0] = __builtin_amdgcn_mfma_f32_16x16x16f16(a0, b0, acc[0][0], 0, 0, 0);
            acc[0][1] = __builtin_amdgcn_mfma_f32_16x16x16f16(a1, b0, acc[0][1], 0, 0, 0);
            acc[0][2] = __builtin_amdgcn_mfma_f32_16x16x16f16(a2, b0, acc[0][2], 0, 0, 0);
            acc[0][3] = __builtin_amdgcn_mfma_f32_16x16x16f16(a3, b0, acc[0][3], 0, 0, 0);
            acc[1][0] = __builtin_amdgcn_mfma_f32_16x16x16f16(a0, b1, acc[1][0], 0, 0, 0);
            acc[1][1] = __builtin_amdgcn_mfma_f32_16x16x16f16(a1, b1, acc[1][1], 0, 0, 0);
            acc[1][2] = __builtin_amdgcn_mfma_f32_16x16x16f16(a2, b1, acc[1][2], 0, 0, 0);
            acc[1][3] = __builtin_amdgcn_mfma_f32_16x16x16f16(a3, b1, acc[1][3], 0, 0, 0);
        }
    }

    #pragma unroll
    for (int rt = 0; rt < 2; ++rt) {
        int row = rowBase + (wave * 2 + rt) * 16 + li;
        if (row < n_nodes) {
            float nr = rsqrtf(fmaxf((float)out_deg[row], 1.0f));
            #pragma unroll
            for (int ct = 0; ct < 4; ++ct) {
                f32x4 dv = acc[rt][ct];
                union { __half2 h2[2]; uint2 u; } pk;
                pk.h2[0] = __floats2half2_rn(dv[0] * nr, dv[1] * nr);
                pk.h2[1] = __floats2half2_rn(dv[2] * nr, dv[3] * nr);
                *(uint2*)(m + (size_t)row * OUT_DIM + ct * 16 + lg * 4) = pk.u;
            }
        }
    }
}

// ---------------------------------------------------------------------------
// K3: fused bucket2csr + gather, half-bucket blocks (round-8 version,
// bit-identical: measured 105 us, DRAM random-line-rate bound).
// ---------------------------------------------------------------------------
__global__ void __launch_bounds__(512) bucket_gather_kernel(
        const unsigned* __restrict__ pairs, const int* __restrict__ dcursor,
        const __half* __restrict__ m, const float* __restrict__ b,
        float* __restrict__ out, int n_nodes, int cap) {
    __shared__ int cnt[GROWS];      // per-row edge count (within half)
    __shared__ int rofs[GROWS];     // inclusive scan of cnt
    __shared__ int cur[GROWS];      // scatter cursor
    __shared__ int csr[CSR_CAP];    // row-sorted src ids (20 KB)

    const int t = threadIdx.x;
    const int bkt = blockIdx.x >> 1;        // parent 256-row bucket
    const int hsel = blockIdx.x & 1;        // which 128-row half
    const unsigned hbit = (unsigned)hsel << 7;
    const int beg = bkt * cap;
    int len = dcursor[bkt];
    if (len > cap) len = cap;
    const int end = beg + len;
    const int rowBase = bkt * BROWS + hsel * GROWS;

    const int wave = t >> 6;
    const int lane = t & 63;
    const int half = lane >> 5;     // which edge of the pair
    const int c    = lane & 31;     // column pair: cols 2c, 2c+1
    const __half2* __restrict__ m2 = (const __half2*)m;   // row stride 32
    const float2 bb = *(const float2*)(b + 2 * c);

    if (t < GROWS) cnt[t] = 0;
    __syncthreads();

    // ---- phase 1: per-row count of this half's edges
    for (int i = beg + t; i < end; i += 512) {
        unsigned p = pairs[i];
        if ((p & 128u) == hbit) atomicAdd(&cnt[p & 127u], 1);
    }
    __syncthreads();
    // ---- phase 2: inclusive scan (Hillis-Steele over 128)
    if (t < GROWS) rofs[t] = cnt[t];
    __syncthreads();
    #pragma unroll
    for (int d = 1; d < GROWS; d <<= 1) {
        int tv = (t < GROWS && t >= d) ? rofs[t - d] : 0;
        __syncthreads();
        if (t < GROWS) rofs[t] += tv;
        __syncthreads();
    }
    if (t < GROWS) cur[t] = rofs[t] - cnt[t];
    __syncthreads();
    const int tot = rofs[GROWS - 1];

    if (tot <= CSR_CAP) {
        // ---- phase 3: position-scatter src ids into LDS CSR (L2-hot re-read)
        for (int i = beg + t; i < end; i += 512) {
            unsigned p = pairs[i];
            if ((p & 128u) == hbit) {
                int pos = atomicAdd(&cur[p & 127u], 1);
                csr[pos] = (int)(p >> 8);
            }
        }
        __syncthreads();
        // ---- phase 4: dual-row gather + softmax (rA, rB = rA+8 interleaved)
        #pragma unroll 1
        for (int p8 = 0; p8 < GROWS / 16; ++p8) {
            const int rA = wave + 16 * p8;
            const int rB = rA + 8;
            const int eA = rofs[rA]; const int bAe = eA - cnt[rA];
            const int eB = rofs[rB]; const int bBe = eB - cnt[rB];
            float axA = 0.f, ayA = 0.f, axB = 0.f, ayB = 0.f;
            int iA = bAe, iB = bBe;
            while (iA + 16 <= eA && iB + 16 <= eB) {
                int sA[8], sB[8];
                #pragma unroll
                for (int k = 0; k < 8; ++k) sA[k] = csr[iA + 2 * k + half];
                #pragma unroll
                for (int k = 0; k < 8; ++k) sB[k] = csr[iB + 2 * k + half];
                float2 fA[8], fB[8];
                #pragma unroll
                for (int k = 0; k < 8; ++k)
                    fA[k] = __half22float2(m2[(unsigned)(sA[k] * (OUT_DIM / 2) + c)]);
                #pragma unroll
                for (int k = 0; k < 8; ++k)
                    fB[k] = __half22float2(m2[(unsigned)(sB[k] * (OUT_DIM / 2) + c)]);
                #pragma unroll
                for (int k = 0; k < 8; ++k) {
                    axA += fA[k].x; ayA += fA[k].y;
                    axB += fB[k].x; ayB += fB[k].y;
                }
                iA += 16; iB += 16;
            }
            for (; iA + 16 <= eA; iA += 16) {
                int s[8];
                #pragma unroll
                for (int k = 0; k < 8; ++k) s[k] = csr[iA + 2 * k + half];
                float2 f[8];
                #pragma unroll
                for (int k = 0; k < 8; ++k)
                    f[k] = __half22float2(m2[(unsigned)(s[k] * (OUT_DIM / 2) + c)]);
                #pragma unroll
                for (int k = 0; k < 8; ++k) { axA += f[k].x; ayA += f[k].y; }
            }
            for (int e = iA + half; e < eA; e += 2) {
                float2 f = __half22float2(m2[(unsigned)(csr[e] * (OUT_DIM / 2) + c)]);
                axA += f.x; ayA += f.y;
            }
            for (; iB + 16 <= eB; iB += 16) {
                int s[8];
                #pragma unroll
                for (int k = 0; k < 8; ++k) s[k] = csr[iB + 2 * k + half];
                float2 f[8];
                #pragma unroll
                for (int k = 0; k < 8; ++k)
                    f[k] = __half22float2(m2[(unsigned)(s[k] * (OUT_DIM / 2) + c)]);
                #pragma unroll
                for (int k = 0; k < 8; ++k) { axB += f[k].x; ayB += f[k].y; }
            }
            for (int e = iB + half; e < eB; e += 2) {
                float2 f = __half22float2(m2[(unsigned)(csr[e] * (OUT_DIM / 2) + c)]);
                axB += f.x; ayB += f.y;
            }
            #pragma unroll
            for (int which = 0; which < 2; ++which) {
                float ax = which ? axB : axA;
                float ay = which ? ayB : ayA;
                const int r = which ? rB : rA;
                const int row = rowBase + r;
                ax += __shfl_xor(ax, 32, 64);
                ay += __shfl_xor(ay, 32, 64);
                float nd = rsqrtf(fmaxf((float)cnt[r], 1.0f));
                float x0 = ax * nd + bb.x;
                float x1 = ay * nd + bb.y;
                float mx = fmaxf(x0, x1);
                #pragma unroll
                for (int o = 16; o > 0; o >>= 1) mx = fmaxf(mx, __shfl_xor(mx, o, 64));
                float ex0 = expf(x0 - mx), ex1 = expf(x1 - mx);
                float sm = ex0 + ex1;
                #pragma unroll
                for (int o = 16; o > 0; o >>= 1) sm += __shfl_xor(sm, o, 64);
                float ls = logf(sm);
                if (half == 0 && row < n_nodes)
                    *(float2*)(out + (size_t)row * OUT_DIM + 2 * c) =
                        make_float2(x0 - mx - ls, x1 - mx - ls);
            }
        }
    } else {
        // ---- slow fallback (pathological half-bucket > CSR_CAP; never on
        // this input): every lane scans the whole parent segment for its rows.
        for (int r = wave; r < GROWS; r += 8) {
            const int row = rowBase + r;
            if (row >= n_nodes) continue;
            const unsigned match = (unsigned)(hsel * GROWS + r);
            float ax = 0.f, ay = 0.f;
            for (int e = beg; e < end; ++e) {
                unsigned p = pairs[e];
                if ((p & 255u) == match) {
                    float2 f = __half22float2(m2[(unsigned)((p >> 8) * (OUT_DIM / 2) + c)]);
                    ax += f.x; ay += f.y;
                }
            }
            float nd = rsqrtf(fmaxf((float)cnt[r], 1.0f));
            float x0 = ax * nd + bb.x;
            float x1 = ay * nd + bb.y;
            float mx = fmaxf(x0, x1);
            #pragma unroll
            for (int o = 16; o > 0; o >>= 1) mx = fmaxf(mx, __shfl_xor(mx, o, 64));
            float ex0 = expf(x0 - mx), ex1 = expf(x1 - mx);
            float sm = ex0 + ex1;
            #pragma unroll
            for (int o = 16; o > 0; o >>= 1) sm += __shfl_xor(sm, o, 64);
            float ls = logf(sm);
            if (half == 0)
                *(float2*)(out + (size_t)row * OUT_DIM + 2 * c) =
                    make_float2(x0 - mx - ls, x1 - mx - ls);
        }
    }
}

// ---------------------------------------------------------------------------
static inline size_t align16(size_t x) { return (x + 15) & ~(size_t)15; }

extern "C" void kernel_launch(void* const* d_in, const int* in_sizes, int n_in,
                              void* d_out, int out_size, void* d_ws, size_t ws_size,
                              hipStream_t stream) {
    const float* h = (const float*)d_in[0];
    const float* W = (const float*)d_in[1];
    const float* b = (const float*)d_in[2];
    const int* edges = (const int*)d_in[3];

    const int out_dim = in_sizes[2];            // 64
    const int in_dim  = in_sizes[1] / out_dim;  // 256
    const int n_nodes = in_sizes[0] / in_dim;   // 100000
    const int n_edges = in_sizes[3] / 2;        // 3200000

    const int* src = edges;
    const int* dst = edges + n_edges;

    float* out = (float*)d_out;

    const int nb = (n_nodes + BROWS - 1) / BROWS;  // 391 buckets

    // fixed bucket segment capacity: mean + 25% + 1024, then 1K-align.
    const int epb = (n_edges + nb - 1) / nb;
    const int cap = (epb + (epb >> 2) + 1023 + 1023) & ~1023;

    // workspace carve-up. out_deg and dcursor are adjacent -> one memset
    // zeroes both (n_nodes*4 = 400000 is 16-aligned, no gap).
    char* ws = (char*)d_ws;
    size_t off = 0;
    int* out_deg     = (int*)(ws + off); off = align16(off + (size_t)n_nodes * 4);
    int* dcursor     = (int*)(ws + off); off = align16(off + (size_t)nb * 4);
    __half* m        = (__half*)(ws + off); off = align16(off + (size_t)n_nodes * OUT_DIM * 2);
    unsigned* pairs  = (unsigned*)(ws + off); off = align16(off + (size_t)nb * cap * 4);

    // zero out_deg + dcursor in one shot
    (void)hipMemsetAsync(out_deg, 0,
                         (size_t)((char*)(dcursor + nb) - (char*)out_deg), stream);

    const int sc_blocks = (n_edges + SC_EDGES - 1) / SC_EDGES;

    scatter_pairs_kernel<<<sc_blocks, SC_THREADS, 0, stream>>>(
        src, dst, dcursor, out_deg, pairs, n_edges, nb, cap);

    gemm_kernel<<<(n_nodes + BM - 1) / BM, 256, 0, stream>>>(
        h, W, out_deg, m, n_nodes);

    bucket_gather_kernel<<<2 * nb, 512, 0, stream>>>(pairs, dcursor, m, b, out,
                                                     n_nodes, cap);
}

// Round 12
// 396.734 us; speedup vs baseline: 1.1272x; 1.1272x over previous
//
#include <hip/hip_runtime.h>
#include <hip/hip_fp16.h>
#include <math.h>

#define IN_DIM 256
#define OUT_DIM 64
#define BROWS 256             // nodes per bucket (pairs format)
#define GROWS 128             // rows per gather block (half bucket)
#define SC_THREADS 512
#define SC_EPB 16
#define SC_EDGES (SC_THREADS * SC_EPB)  // 8192 edges per scatter block (391 blocks - proven best)
#define BM 128                // gemm rows per block
#define KC2 64                // gemm k-chunk (fp16 MFMA version)
#define LDH 68                // padded fp16 leading dim (136 B = 17*8, b64-aligned)
#define CSR_CAP 5120          // LDS CSR capacity per half-bucket (mean 4092, sigma ~64)
#define NSLICE 4              // src slices (src>>15): <=4 MB of m per slice (~= per-XCD L2)
#define NKEY (GROWS * NSLICE) // 512 (row,slice) keys: one scan element per thread

typedef _Float16 f16x4 __attribute__((ext_vector_type(4)));
typedef float f32x4 __attribute__((ext_vector_type(4)));

// ---------------------------------------------------------------------------
// K1: dual multisplit with fixed-capacity segments + LDS-staged COALESCED
// writes (round-8 version, byte-identical — measured best; ~51 us inferred).
// ---------------------------------------------------------------------------
__global__ void __launch_bounds__(SC_THREADS) scatter_pairs_kernel(
        const int* __restrict__ src, const int* __restrict__ dst,
        int* __restrict__ dcursor, int* __restrict__ scursor,
        unsigned* __restrict__ pairs, unsigned char* __restrict__ sbytes,
        int n_edges, int nb, int cap) {
    __shared__ int lhd[512];            // dst: per-bucket count (kept)
    __shared__ int lbd[512];            // dst: reserved global base
    __shared__ int lod[512];            // dst: staged offset -> staging cursor -> end
    __shared__ int lhs[512];            // src side, same roles
    __shared__ int lbs[512];
    __shared__ int los[512];
    __shared__ unsigned stp[SC_EDGES];       // staged pairs, 32 KB
    __shared__ unsigned char stb[SC_EDGES];  // staged src bytes, 8 KB

    const int t = threadIdx.x;
    const int wave = t >> 6;
    const int lane = t & 63;

    lhd[t] = 0; lhs[t] = 0;
    __syncthreads();

    // ---- load edges into regs + per-bucket counts
    const int base = blockIdx.x * SC_EDGES;
    int s[SC_EPB], d[SC_EPB];
    if (base + SC_EDGES <= n_edges) {
        const int4* s4 = (const int4*)(src + base);
        const int4* d4 = (const int4*)(dst + base);
        #pragma unroll
        for (int j = 0; j < SC_EPB / 4; ++j) {
            int4 a = s4[j * SC_THREADS + t];
            int4 c = d4[j * SC_THREADS + t];
            s[4*j+0] = a.x; s[4*j+1] = a.y; s[4*j+2] = a.z; s[4*j+3] = a.w;
            d[4*j+0] = c.x; d[4*j+1] = c.y; d[4*j+2] = c.z; d[4*j+3] = c.w;
        }
        #pragma unroll
        for (int i = 0; i < SC_EPB; ++i) {
            atomicAdd(&lhd[d[i] >> 8], 1);
            atomicAdd(&lhs[s[i] >> 8], 1);
        }
    } else {
        #pragma unroll
        for (int i = 0; i < SC_EPB; ++i) {
            int e = base + i * SC_THREADS + t;
            if (e < n_edges) {
                s[i] = src[e];
                d[i] = dst[e];
                atomicAdd(&lhd[d[i] >> 8], 1);
                atomicAdd(&lhs[s[i] >> 8], 1);
            } else {
                s[i] = -1; d[i] = 0;
            }
        }
    }
    __syncthreads();

    // ---- reserve global chunks (one atomic per (block,bucket) per split)
    for (int i = t; i < nb; i += SC_THREADS) {
        int c = lhd[i];
        lbd[i] = c ? atomicAdd(&dcursor[i], c) : 0;
        c = lhs[i];
        lbs[i] = c ? atomicAdd(&scursor[i], c) : 0;
    }

    // ---- block-local exclusive scans (both splits interleaved)
    {
        int vd = (t < nb) ? lhd[t] : 0;
        int vs = (t < nb) ? lhs[t] : 0;
        lod[t] = vd; los[t] = vs;
        __syncthreads();
        #pragma unroll
        for (int dd = 1; dd < 512; dd <<= 1) {
            int td = (t >= dd) ? lod[t - dd] : 0;
            int ts = (t >= dd) ? los[t - dd] : 0;
            __syncthreads();
            lod[t] += td; los[t] += ts;
            __syncthreads();
        }
        lod[t] -= vd; los[t] -= vs;     // own-element: no hazard
    }
    __syncthreads();

    // ---- stage bucket-sorted into LDS (lod/los advance to run ends)
    #pragma unroll
    for (int i = 0; i < SC_EPB; ++i) {
        if (s[i] >= 0) {
            int bkt = d[i] >> 8;
            int pos = atomicAdd(&lod[bkt], 1);
            stp[pos] = ((unsigned)s[i] << 8) | (unsigned)(d[i] & 255);
            int sb = s[i] >> 8;
            int spos = atomicAdd(&los[sb], 1);
            stb[spos] = (unsigned char)(s[i] & 255);
        }
    }
    __syncthreads();

    // ---- coalesced copy-out: wave per bucket run
    for (int b2 = wave; b2 < nb; b2 += SC_THREADS / 64) {
        int cnt = lhd[b2];
        if (cnt) {
            int st = lod[b2] - cnt;           // run start in staging
            int gb = lbd[b2];                 // offset within bucket slot
            unsigned* gp = pairs + (size_t)b2 * cap;
            for (int j = lane; j < cnt; j += 64)
                if (gb + j < cap) gp[gb + j] = stp[st + j];
        }
        cnt = lhs[b2];
        if (cnt) {
            int st = los[b2] - cnt;
            int gb = lbs[b2];
            unsigned char* gp = sbytes + (size_t)b2 * cap;
            for (int j = lane; j < cnt; j += 64)
                if (gb + j < cap) gp[gb + j] = stb[st + j];
        }
    }
}

// ---------------------------------------------------------------------------
// K2: out_deg from src-bucket bytes (round-8 version, unchanged).
// ---------------------------------------------------------------------------
__global__ void __launch_bounds__(256) count_src_kernel(
        const unsigned char* __restrict__ sbytes, const int* __restrict__ scursor,
        int* __restrict__ out_deg, int n_nodes, int cap) {
    __shared__ int cnt[BROWS];
    cnt[threadIdx.x] = 0;
    __syncthreads();
    const int beg = blockIdx.x * cap;
    int len = scursor[blockIdx.x];
    if (len > cap) len = cap;
    const int end = beg + len;
    for (int i = beg + threadIdx.x; i < end; i += 256)
        atomicAdd(&cnt[sbytes[i]], 1);
    __syncthreads();
    const int row = blockIdx.x * BROWS + threadIdx.x;
    if (row < n_nodes) out_deg[row] = cnt[threadIdx.x];
}

// ---------------------------------------------------------------------------
// K3: MFMA GEMM (round-8 version, unchanged). fp16 in, fp32 accumulate,
// operand-swapped so each lane's D = 4 consecutive output cols of one row.
// ---------------------------------------------------------------------------
__global__ void __launch_bounds__(256) gemm_kernel(
        const float* __restrict__ h, const float* __restrict__ W,
        const int* __restrict__ out_deg, __half* __restrict__ m, int n_nodes) {
    __shared__ _Float16 hs[BM * LDH];        // 128 x 68 fp16 = 17.4 KB
    __shared__ _Float16 Wt[OUT_DIM * LDH];   // 64 x 68 fp16 = 8.7 KB (transposed)

    const int t = threadIdx.x;
    const int wave = t >> 6;
    const int lane = t & 63;
    const int lg = lane >> 4;       // k-subgroup / D col-subgroup
    const int li = lane & 15;       // A-row (out col) / B-col (node row)
    const int rowBase = blockIdx.x * BM;

    f32x4 acc[2][4];
    #pragma unroll
    for (int rt = 0; rt < 2; ++rt)
        #pragma unroll
        for (int ct = 0; ct < 4; ++ct)
            acc[rt][ct] = (f32x4){0.f, 0.f, 0.f, 0.f};

    for (int kc = 0; kc < IN_DIM / KC2; ++kc) {
        __syncthreads();
        // ---- stage hs: 128 rows x 64 k, fp32 -> fp16 (float4 loads)
        #pragma unroll
        for (int i = 0; i < 8; ++i) {
            int idx = t + 256 * i;          // 2048 float4s
            int row = idx >> 4;             // 16 float4 per row
            int s4 = idx & 15;
            float4 v = make_float4(0.f, 0.f, 0.f, 0.f);
            if (rowBase + row < n_nodes)
                v = *(const float4*)(h + (size_t)(rowBase + row) * IN_DIM
                                     + kc * KC2 + s4 * 4);
            _Float16* dp = &hs[row * LDH + s4 * 4];
            dp[0] = (_Float16)v.x; dp[1] = (_Float16)v.y;
            dp[2] = (_Float16)v.z; dp[3] = (_Float16)v.w;
        }
        // ---- stage Wt transposed: Wt[n][k] = W[kc*64+k][n], fp32 -> fp16
        #pragma unroll
        for (int i = 0; i < 16; ++i) {
            int idx = t + 256 * i;          // 4096 elems
            int k = idx >> 6;
            int n = idx & 63;
            Wt[n * LDH + k] = (_Float16)W[(size_t)(kc * KC2 + k) * OUT_DIM + n];
        }
        __syncthreads();

        #pragma unroll
        for (int ks = 0; ks < KC2 / 16; ++ks) {
            const int k0 = ks * 16 + lg * 4;
            f16x4 b0 = *(const f16x4*)&hs[((wave * 2 + 0) * 16 + li) * LDH + k0];
            f16x4 b1 = *(const f16x4*)&hs[((wave * 2 + 1) * 16 + li) * LDH + k0];
            f16x4 a0 = *(const f16x4*)&Wt[(0 * 16 + li) * LDH + k0];
            f16x4 a1 = *(const f16x4*)&Wt[(1 * 16 + li) * LDH + k0];
            f16x4 a2 = *(const f16x4*)&Wt[(2 * 16 + li) * LDH + k0];
            f16x4 a3 = *(const f16x4*)&Wt[(3 * 16 + li) * LDH + k0];
            acc[0][0] = __builtin_amdgcn_mfma_f32_16x16x16f16(a0, b0, acc[0][0], 0, 0, 0);
            acc[0][1] = __builtin_amdgcn_mfma_f32_16x16x16f16(a1, b0, acc[0][1], 0, 0, 0);
            acc[0][2] = __builtin_amdgcn_mfma_f32_16x16x16f16(a2, b0, acc[0][2], 0, 0, 0);
            acc[0][3] = __builtin_amdgcn_mfma_f32_16x16x16f16(a3, b0, acc[0][3], 0, 0, 0);
            acc[1][0] = __builtin_amdgcn_mfma_f32_16x16x16f16(a0, b1, acc[1][0], 0, 0, 0);
            acc[1][1] = __builtin_amdgcn_mfma_f32_16x16x16f16(a1, b1, acc[1][1], 0, 0, 0);
            acc[1][2] = __builtin_amdgcn_mfma_f32_16x16x16f16(a2, b1, acc[1][2], 0, 0, 0);
            acc[1][3] = __builtin_amdgcn_mfma_f32_16x16x16f16(a3, b1, acc[1][3], 0, 0, 0);
        }
    }

    #pragma unroll
    for (int rt = 0; rt < 2; ++rt) {
        int row = rowBase + (wave * 2 + rt) * 16 + li;
        if (row < n_nodes) {
            float nr = rsqrtf(fmaxf((float)out_deg[row], 1.0f));
            #pragma unroll
            for (int ct = 0; ct < 4; ++ct) {
                f32x4 dv = acc[rt][ct];
                union { __half2 h2[2]; uint2 u; } pk;
                pk.h2[0] = __floats2half2_rn(dv[0] * nr, dv[1] * nr);
                pk.h2[1] = __floats2half2_rn(dv[2] * nr, dv[3] * nr);
                *(uint2*)(m + (size_t)row * OUT_DIM + ct * 16 + lg * 4) = pk.u;
            }
        }
    }
}

// ---------------------------------------------------------------------------
// K4: fused bucket2csr + gather with NSLICE=4 slice-swept phase 4.
// Fixes both R9 failure modes: (a) NSLICE 8->4 (mean segment 4->8 edges,
// half the per-segment overhead; 512 keys = 1 scan elem/thread);
// (b) accumulator arrays fully unrolled (compile-time indices -> VGPRs,
// not scratch — R9's VGPR=32 betrayed a rule-#20 spill). Batch loop keeps
// R8's uniform condition (half offset only in the index) and 8 loads in
// flight (4 per row, dual-row).
// ---------------------------------------------------------------------------
__global__ void __launch_bounds__(512) bucket_gather_kernel(
        const unsigned* __restrict__ pairs, const int* __restrict__ dcursor,
        const __half* __restrict__ m, const float* __restrict__ b,
        float* __restrict__ out, int n_nodes, int cap) {
    __shared__ int cnt[NKEY];       // per-(row,slice) edge count (2 KB)
    __shared__ int rofs[NKEY];      // inclusive scan of cnt (2 KB)
    __shared__ int cur[NKEY];       // scatter cursor (2 KB)
    __shared__ int csr[CSR_CAP];    // (row,slice)-sorted src ids (20 KB)

    const int t = threadIdx.x;
    const int bkt = blockIdx.x >> 1;        // parent 256-row bucket
    const int hsel = blockIdx.x & 1;        // which 128-row half
    const unsigned hbit = (unsigned)hsel << 7;
    const int beg = bkt * cap;
    int len = dcursor[bkt];
    if (len > cap) len = cap;
    const int end = beg + len;
    const int rowBase = bkt * BROWS + hsel * GROWS;

    const int wave = t >> 6;
    const int lane = t & 63;
    const int half = lane >> 5;     // which edge of the pair
    const int c    = lane & 31;     // column pair: cols 2c, 2c+1
    const __half2* __restrict__ m2 = (const __half2*)m;   // row stride 32
    const float2 bb = *(const float2*)(b + 2 * c);

    cnt[t] = 0;
    __syncthreads();

    // ---- phase 1: per-(row,slice) count. key = (p&127)*4 + (src>>15)
    // src bit 15 = p bit 23 (p = src<<8 | dstbyte); src<2^17 -> slice 0..3
    for (int i = beg + t; i < end; i += 512) {
        unsigned p = pairs[i];
        if ((p & 128u) == hbit)
            atomicAdd(&cnt[(int)(p & 127u) * NSLICE + (int)((p >> 23) & 3u)], 1);
    }
    __syncthreads();
    // ---- phase 2: inclusive scan over 512 keys (one element per thread)
    {
        int v = cnt[t];
        rofs[t] = v;
        __syncthreads();
        #pragma unroll
        for (int d = 1; d < NKEY; d <<= 1) {
            int tv = (t >= d) ? rofs[t - d] : 0;
            __syncthreads();
            rofs[t] += tv;
            __syncthreads();
        }
        cur[t] = rofs[t] - v;
    }
    __syncthreads();
    const int tot = rofs[NKEY - 1];

    if (tot <= CSR_CAP) {
        // ---- phase 3: position-scatter src ids into LDS CSR (L2-hot re-read)
        for (int i = beg + t; i < end; i += 512) {
            unsigned p = pairs[i];
            if ((p & 128u) == hbit) {
                int key = (int)(p & 127u) * NSLICE + (int)((p >> 23) & 3u);
                int pos = atomicAdd(&cur[key], 1);
                csr[pos] = (int)(p >> 8);
            }
        }
        __syncthreads();
        // ---- phase 4: slice-swept dual-row gather. Accumulators for the
        // wave's 16 rows live in registers across the slice sweep.
        float ax[16], ay[16];
        #pragma unroll
        for (int j = 0; j < 16; ++j) { ax[j] = 0.f; ay[j] = 0.f; }

        #pragma unroll 1
        for (int s = 0; s < NSLICE; ++s) {
            #pragma unroll
            for (int q = 0; q < 8; ++q) {
                const int jA = 2 * q, jB = 2 * q + 1;
                const int kA = (wave + 8 * jA) * NSLICE + s;
                const int kB = (wave + 8 * jB) * NSLICE + s;
                const int eA = rofs[kA]; int iA = eA - cnt[kA];
                const int eB = rofs[kB]; int iB = eB - cnt[kB];
                float axA = 0.f, ayA = 0.f, axB = 0.f, ayB = 0.f;
                // batch-4 dual-row: 8 loads in flight, uniform loop condition
                while (iA + 8 <= eA && iB + 8 <= eB) {
                    int sA[4], sB[4];
                    #pragma unroll
                    for (int k = 0; k < 4; ++k) sA[k] = csr[iA + 2 * k + half];
                    #pragma unroll
                    for (int k = 0; k < 4; ++k) sB[k] = csr[iB + 2 * k + half];
                    float2 fA[4], fB[4];
                    #pragma unroll
                    for (int k = 0; k < 4; ++k)
                        fA[k] = __half22float2(m2[(unsigned)(sA[k] * (OUT_DIM / 2) + c)]);
                    #pragma unroll
                    for (int k = 0; k < 4; ++k)
                        fB[k] = __half22float2(m2[(unsigned)(sB[k] * (OUT_DIM / 2) + c)]);
                    #pragma unroll
                    for (int k = 0; k < 4; ++k) {
                        axA += fA[k].x; ayA += fA[k].y;
                        axB += fB[k].x; ayB += fB[k].y;
                    }
                    iA += 8; iB += 8;
                }
                for (; iA + 8 <= eA; iA += 8) {
                    int sA[4];
                    #pragma unroll
                    for (int k = 0; k < 4; ++k) sA[k] = csr[iA + 2 * k + half];
                    #pragma unroll
                    for (int k = 0; k < 4; ++k) {
                        float2 f = __half22float2(m2[(unsigned)(sA[k] * (OUT_DIM / 2) + c)]);
                        axA += f.x; ayA += f.y;
                    }
                }
                for (int e = iA + half; e < eA; e += 2) {
                    float2 f = __half22float2(m2[(unsigned)(csr[e] * (OUT_DIM / 2) + c)]);
                    axA += f.x; ayA += f.y;
                }
                for (; iB + 8 <= eB; iB += 8) {
                    int sB[4];
                    #pragma unroll
                    for (int k = 0; k < 4; ++k) sB[k] = csr[iB + 2 * k + half];
                    #pragma unroll
                    for (int k = 0; k < 4; ++k) {
                        float2 f = __half22float2(m2[(unsigned)(sB[k] * (OUT_DIM / 2) + c)]);
                        axB += f.x; ayB += f.y;
                    }
                }
                for (int e = iB + half; e < eB; e += 2) {
                    float2 f = __half22float2(m2[(unsigned)(csr[e] * (OUT_DIM / 2) + c)]);
                    axB += f.x; ayB += f.y;
                }
                ax[jA] += axA; ay[jA] += ayA;
                ax[jB] += axB; ay[jB] += ayB;
            }
        }

        // ---- epilogue: combine halves + softmax + store (fully unrolled)
        #pragma unroll
        for (int j = 0; j < 16; ++j) {
            const int r = wave + 8 * j;
            const int row = rowBase + r;
            float axv = ax[j], ayv = ay[j];
            axv += __shfl_xor(axv, 32, 64);
            ayv += __shfl_xor(ayv, 32, 64);
            const int deg = rofs[r * NSLICE + NSLICE - 1]
                          - (rofs[r * NSLICE] - cnt[r * NSLICE]);
            float nd = rsqrtf(fmaxf((float)deg, 1.0f));
            float x0 = axv * nd + bb.x;
            float x1 = ayv * nd + bb.y;
            float mx = fmaxf(x0, x1);
            #pragma unroll
            for (int o = 16; o > 0; o >>= 1) mx = fmaxf(mx, __shfl_xor(mx, o, 64));
            float ex0 = expf(x0 - mx), ex1 = expf(x1 - mx);
            float sm = ex0 + ex1;
            #pragma unroll
            for (int o = 16; o > 0; o >>= 1) sm += __shfl_xor(sm, o, 64);
            float ls = logf(sm);
            if (half == 0 && row < n_nodes)
                *(float2*)(out + (size_t)row * OUT_DIM + 2 * c) =
                    make_float2(x0 - mx - ls, x1 - mx - ls);
        }
    } else {
        // ---- slow fallback (pathological half-bucket > CSR_CAP; never on
        // this input): every lane scans the whole parent segment for its rows.
        for (int r = wave; r < GROWS; r += 8) {
            const int row = rowBase + r;
            if (row >= n_nodes) continue;
            const unsigned match = (unsigned)(hsel * GROWS + r);
            float axv = 0.f, ayv = 0.f;
            for (int e = beg; e < end; ++e) {
                unsigned p = pairs[e];
                if ((p & 255u) == match) {
                    float2 f = __half22float2(m2[(unsigned)((p >> 8) * (OUT_DIM / 2) + c)]);
                    axv += f.x; ayv += f.y;
                }
            }
            const int deg = rofs[r * NSLICE + NSLICE - 1]
                          - (rofs[r * NSLICE] - cnt[r * NSLICE]);
            float nd = rsqrtf(fmaxf((float)deg, 1.0f));
            float x0 = axv * nd + bb.x;
            float x1 = ayv * nd + bb.y;
            float mx = fmaxf(x0, x1);
            #pragma unroll
            for (int o = 16; o > 0; o >>= 1) mx = fmaxf(mx, __shfl_xor(mx, o, 64));
            float ex0 = expf(x0 - mx), ex1 = expf(x1 - mx);
            float sm = ex0 + ex1;
            #pragma unroll
            for (int o = 16; o > 0; o >>= 1) sm += __shfl_xor(sm, o, 64);
            float ls = logf(sm);
            if (half == 0)
                *(float2*)(out + (size_t)row * OUT_DIM + 2 * c) =
                    make_float2(x0 - mx - ls, x1 - mx - ls);
        }
    }
}

// ---------------------------------------------------------------------------
static inline size_t align16(size_t x) { return (x + 15) & ~(size_t)15; }

extern "C" void kernel_launch(void* const* d_in, const int* in_sizes, int n_in,
                              void* d_out, int out_size, void* d_ws, size_t ws_size,
                              hipStream_t stream) {
    const float* h = (const float*)d_in[0];
    const float* W = (const float*)d_in[1];
    const float* b = (const float*)d_in[2];
    const int* edges = (const int*)d_in[3];

    const int out_dim = in_sizes[2];            // 64
    const int in_dim  = in_sizes[1] / out_dim;  // 256
    const int n_nodes = in_sizes[0] / in_dim;   // 100000
    const int n_edges = in_sizes[3] / 2;        // 3200000

    const int* src = edges;
    const int* dst = edges + n_edges;

    float* out = (float*)d_out;

    const int nb = (n_nodes + BROWS - 1) / BROWS;  // 391 buckets

    // fixed bucket segment capacity: mean + 25% + 1024, then 1K-align.
    const int epb = (n_edges + nb - 1) / nb;
    const int cap = (epb + (epb >> 2) + 1023 + 1023) & ~1023;

    // workspace carve-up (round-8 layout)
    char* ws = (char*)d_ws;
    size_t off = 0;
    int* out_deg     = (int*)(ws + off); off = align16(off + (size_t)n_nodes * 4);
    int* dcursor     = (int*)(ws + off); off = align16(off + (size_t)nb * 4);
    int* scursor     = (int*)(ws + off); off = align16(off + (size_t)nb * 4);
    __half* m        = (__half*)(ws + off); off = align16(off + (size_t)n_nodes * OUT_DIM * 2);
    unsigned* pairs  = (unsigned*)(ws + off); off = align16(off + (size_t)nb * cap * 4);
    // sbytes aliases m's storage (scatter writes, count_src reads, both
    // before gemm writes m; serial stream ordering). nb*cap (4 MB) <= 12.8 MB.
    unsigned char* sbytes = (unsigned char*)m;

    // zero both cursor arrays (contiguous)
    (void)hipMemsetAsync(dcursor, 0,
                         (size_t)((char*)(scursor + nb) - (char*)dcursor), stream);

    const int sc_blocks = (n_edges + SC_EDGES - 1) / SC_EDGES;

    scatter_pairs_kernel<<<sc_blocks, SC_THREADS, 0, stream>>>(
        src, dst, dcursor, scursor, pairs, sbytes, n_edges, nb, cap);
    count_src_kernel<<<nb, 256, 0, stream>>>(sbytes, scursor, out_deg, n_nodes, cap);

    gemm_kernel<<<(n_nodes + BM - 1) / BM, 256, 0, stream>>>(
        h, W, out_deg, m, n_nodes);

    bucket_gather_kernel<<<2 * nb, 512, 0, stream>>>(pairs, dcursor, m, b, out,
                                                     n_nodes, cap);
}

// Round 13
// 359.330 us; speedup vs baseline: 1.2446x; 1.1041x over previous
//
#include <hip/hip_runtime.h>
#include <hip/hip_fp16.h>
#include <math.h>

#define IN_DIM 256
#define OUT_DIM 64
#define BROWS 256             // nodes per bucket (pairs format)
#define GROWS 128             // rows per gather block (half bucket)
#define SC_THREADS 512
#define SC_EPB 16
#define SC_EDGES (SC_THREADS * SC_EPB)  // 8192 edges per scatter block (391 blocks - proven best)
#define BM 128                // gemm rows per block
#define KC2 64                // gemm k-chunk (fp16 MFMA version)
#define LDH 68                // padded fp16 leading dim (136 B = 17*8, b64-aligned)
#define CSR_CAP 5120          // LDS CSR capacity per half-bucket (mean 4092, sigma ~64)

typedef _Float16 f16x4 __attribute__((ext_vector_type(4)));
typedef float f32x4 __attribute__((ext_vector_type(4)));

// ---------------------------------------------------------------------------
// K1: dual multisplit with fixed-capacity segments + LDS-staged COALESCED
// writes (round-8 version, byte-identical — measured-best configuration).
// ---------------------------------------------------------------------------
__global__ void __launch_bounds__(SC_THREADS) scatter_pairs_kernel(
        const int* __restrict__ src, const int* __restrict__ dst,
        int* __restrict__ dcursor, int* __restrict__ scursor,
        unsigned* __restrict__ pairs, unsigned char* __restrict__ sbytes,
        int n_edges, int nb, int cap) {
    __shared__ int lhd[512];            // dst: per-bucket count (kept)
    __shared__ int lbd[512];            // dst: reserved global base
    __shared__ int lod[512];            // dst: staged offset -> staging cursor -> end
    __shared__ int lhs[512];            // src side, same roles
    __shared__ int lbs[512];
    __shared__ int los[512];
    __shared__ unsigned stp[SC_EDGES];       // staged pairs, 32 KB
    __shared__ unsigned char stb[SC_EDGES];  // staged src bytes, 8 KB

    const int t = threadIdx.x;
    const int wave = t >> 6;
    const int lane = t & 63;

    lhd[t] = 0; lhs[t] = 0;
    __syncthreads();

    // ---- load edges into regs + per-bucket counts
    const int base = blockIdx.x * SC_EDGES;
    int s[SC_EPB], d[SC_EPB];
    if (base + SC_EDGES <= n_edges) {
        const int4* s4 = (const int4*)(src + base);
        const int4* d4 = (const int4*)(dst + base);
        #pragma unroll
        for (int j = 0; j < SC_EPB / 4; ++j) {
            int4 a = s4[j * SC_THREADS + t];
            int4 c = d4[j * SC_THREADS + t];
            s[4*j+0] = a.x; s[4*j+1] = a.y; s[4*j+2] = a.z; s[4*j+3] = a.w;
            d[4*j+0] = c.x; d[4*j+1] = c.y; d[4*j+2] = c.z; d[4*j+3] = c.w;
        }
        #pragma unroll
        for (int i = 0; i < SC_EPB; ++i) {
            atomicAdd(&lhd[d[i] >> 8], 1);
            atomicAdd(&lhs[s[i] >> 8], 1);
        }
    } else {
        #pragma unroll
        for (int i = 0; i < SC_EPB; ++i) {
            int e = base + i * SC_THREADS + t;
            if (e < n_edges) {
                s[i] = src[e];
                d[i] = dst[e];
                atomicAdd(&lhd[d[i] >> 8], 1);
                atomicAdd(&lhs[s[i] >> 8], 1);
            } else {
                s[i] = -1; d[i] = 0;
            }
        }
    }
    __syncthreads();

    // ---- reserve global chunks (one atomic per (block,bucket) per split)
    for (int i = t; i < nb; i += SC_THREADS) {
        int c = lhd[i];
        lbd[i] = c ? atomicAdd(&dcursor[i], c) : 0;
        c = lhs[i];
        lbs[i] = c ? atomicAdd(&scursor[i], c) : 0;
    }

    // ---- block-local exclusive scans (both splits interleaved)
    {
        int vd = (t < nb) ? lhd[t] : 0;
        int vs = (t < nb) ? lhs[t] : 0;
        lod[t] = vd; los[t] = vs;
        __syncthreads();
        #pragma unroll
        for (int dd = 1; dd < 512; dd <<= 1) {
            int td = (t >= dd) ? lod[t - dd] : 0;
            int ts = (t >= dd) ? los[t - dd] : 0;
            __syncthreads();
            lod[t] += td; los[t] += ts;
            __syncthreads();
        }
        lod[t] -= vd; los[t] -= vs;     // own-element: no hazard
    }
    __syncthreads();

    // ---- stage bucket-sorted into LDS (lod/los advance to run ends)
    #pragma unroll
    for (int i = 0; i < SC_EPB; ++i) {
        if (s[i] >= 0) {
            int bkt = d[i] >> 8;
            int pos = atomicAdd(&lod[bkt], 1);
            stp[pos] = ((unsigned)s[i] << 8) | (unsigned)(d[i] & 255);
            int sb = s[i] >> 8;
            int spos = atomicAdd(&los[sb], 1);
            stb[spos] = (unsigned char)(s[i] & 255);
        }
    }
    __syncthreads();

    // ---- coalesced copy-out: wave per bucket run
    for (int b2 = wave; b2 < nb; b2 += SC_THREADS / 64) {
        int cnt = lhd[b2];
        if (cnt) {
            int st = lod[b2] - cnt;           // run start in staging
            int gb = lbd[b2];                 // offset within bucket slot
            unsigned* gp = pairs + (size_t)b2 * cap;
            for (int j = lane; j < cnt; j += 64)
                if (gb + j < cap) gp[gb + j] = stp[st + j];
        }
        cnt = lhs[b2];
        if (cnt) {
            int st = los[b2] - cnt;
            int gb = lbs[b2];
            unsigned char* gp = sbytes + (size_t)b2 * cap;
            for (int j = lane; j < cnt; j += 64)
                if (gb + j < cap) gp[gb + j] = stb[st + j];
        }
    }
}

// ---------------------------------------------------------------------------
// K2: out_deg from src-bucket bytes (round-8 version, unchanged).
// ---------------------------------------------------------------------------
__global__ void __launch_bounds__(256) count_src_kernel(
        const unsigned char* __restrict__ sbytes, const int* __restrict__ scursor,
        int* __restrict__ out_deg, int n_nodes, int cap) {
    __shared__ int cnt[BROWS];
    cnt[threadIdx.x] = 0;
    __syncthreads();
    const int beg = blockIdx.x * cap;
    int len = scursor[blockIdx.x];
    if (len > cap) len = cap;
    const int end = beg + len;
    for (int i = beg + threadIdx.x; i < end; i += 256)
        atomicAdd(&cnt[sbytes[i]], 1);
    __syncthreads();
    const int row = blockIdx.x * BROWS + threadIdx.x;
    if (row < n_nodes) out_deg[row] = cnt[threadIdx.x];
}

// ---------------------------------------------------------------------------
// K3: MFMA GEMM (round-8 version, unchanged). fp16 in, fp32 accumulate,
// operand-swapped so each lane's D = 4 consecutive output cols of one row.
// ---------------------------------------------------------------------------
__global__ void __launch_bounds__(256) gemm_kernel(
        const float* __restrict__ h, const float* __restrict__ W,
        const int* __restrict__ out_deg, __half* __restrict__ m, int n_nodes) {
    __shared__ _Float16 hs[BM * LDH];        // 128 x 68 fp16 = 17.4 KB
    __shared__ _Float16 Wt[OUT_DIM * LDH];   // 64 x 68 fp16 = 8.7 KB (transposed)

    const int t = threadIdx.x;
    const int wave = t >> 6;
    const int lane = t & 63;
    const int lg = lane >> 4;       // k-subgroup / D col-subgroup
    const int li = lane & 15;       // A-row (out col) / B-col (node row)
    const int rowBase = blockIdx.x * BM;

    f32x4 acc[2][4];
    #pragma unroll
    for (int rt = 0; rt < 2; ++rt)
        #pragma unroll
        for (int ct = 0; ct < 4; ++ct)
            acc[rt][ct] = (f32x4){0.f, 0.f, 0.f, 0.f};

    for (int kc = 0; kc < IN_DIM / KC2; ++kc) {
        __syncthreads();
        // ---- stage hs: 128 rows x 64 k, fp32 -> fp16 (float4 loads)
        #pragma unroll
        for (int i = 0; i < 8; ++i) {
            int idx = t + 256 * i;          // 2048 float4s
            int row = idx >> 4;             // 16 float4 per row
            int s4 = idx & 15;
            float4 v = make_float4(0.f, 0.f, 0.f, 0.f);
            if (rowBase + row < n_nodes)
                v = *(const float4*)(h + (size_t)(rowBase + row) * IN_DIM
                                     + kc * KC2 + s4 * 4);
            _Float16* dp = &hs[row * LDH + s4 * 4];
            dp[0] = (_Float16)v.x; dp[1] = (_Float16)v.y;
            dp[2] = (_Float16)v.z; dp[3] = (_Float16)v.w;
        }
        // ---- stage Wt transposed: Wt[n][k] = W[kc*64+k][n], fp32 -> fp16
        #pragma unroll
        for (int i = 0; i < 16; ++i) {
            int idx = t + 256 * i;          // 4096 elems
            int k = idx >> 6;
            int n = idx & 63;
            Wt[n * LDH + k] = (_Float16)W[(size_t)(kc * KC2 + k) * OUT_DIM + n];
        }
        __syncthreads();

        #pragma unroll
        for (int ks = 0; ks < KC2 / 16; ++ks) {
            const int k0 = ks * 16 + lg * 4;
            f16x4 b0 = *(const f16x4*)&hs[((wave * 2 + 0) * 16 + li) * LDH + k0];
            f16x4 b1 = *(const f16x4*)&hs[((wave * 2 + 1) * 16 + li) * LDH + k0];
            f16x4 a0 = *(const f16x4*)&Wt[(0 * 16 + li) * LDH + k0];
            f16x4 a1 = *(const f16x4*)&Wt[(1 * 16 + li) * LDH + k0];
            f16x4 a2 = *(const f16x4*)&Wt[(2 * 16 + li) * LDH + k0];
            f16x4 a3 = *(const f16x4*)&Wt[(3 * 16 + li) * LDH + k0];
            acc[0][0] = __builtin_amdgcn_mfma_f32_16x16x16f16(a0, b0, acc[0][0], 0, 0, 0);
            acc[0][1] = __builtin_amdgcn_mfma_f32_16x16x16f16(a1, b0, acc[0][1], 0, 0, 0);
            acc[0][2] = __builtin_amdgcn_mfma_f32_16x16x16f16(a2, b0, acc[0][2], 0, 0, 0);
            acc[0][3] = __builtin_amdgcn_mfma_f32_16x16x16f16(a3, b0, acc[0][3], 0, 0, 0);
            acc[1][0] = __builtin_amdgcn_mfma_f32_16x16x16f16(a0, b1, acc[1][0], 0, 0, 0);
            acc[1][1] = __builtin_amdgcn_mfma_f32_16x16x16f16(a1, b1, acc[1][1], 0, 0, 0);
            acc[1][2] = __builtin_amdgcn_mfma_f32_16x16x16f16(a2, b1, acc[1][2], 0, 0, 0);
            acc[1][3] = __builtin_amdgcn_mfma_f32_16x16x16f16(a3, b1, acc[1][3], 0, 0, 0);
        }
    }

    #pragma unroll
    for (int rt = 0; rt < 2; ++rt) {
        int row = rowBase + (wave * 2 + rt) * 16 + li;
        if (row < n_nodes) {
            float nr = rsqrtf(fmaxf((float)out_deg[row], 1.0f));
            #pragma unroll
            for (int ct = 0; ct < 4; ++ct) {
                f32x4 dv = acc[rt][ct];
                union { __half2 h2[2]; uint2 u; } pk;
                pk.h2[0] = __floats2half2_rn(dv[0] * nr, dv[1] * nr);
                pk.h2[1] = __floats2half2_rn(dv[2] * nr, dv[3] * nr);
                *(uint2*)(m + (size_t)row * OUT_DIM + ct * 16 + lg * 4) = pk.u;
            }
        }
    }
}

// ---------------------------------------------------------------------------
// K4: fused bucket2csr + gather, half-bucket blocks (round-8 version,
// bit-identical: measured 105-106 us, random-128B-line DRAM-frontier bound).
// ---------------------------------------------------------------------------
__global__ void __launch_bounds__(512) bucket_gather_kernel(
        const unsigned* __restrict__ pairs, const int* __restrict__ dcursor,
        const __half* __restrict__ m, const float* __restrict__ b,
        float* __restrict__ out, int n_nodes, int cap) {
    __shared__ int cnt[GROWS];      // per-row edge count (within half)
    __shared__ int rofs[GROWS];     // inclusive scan of cnt
    __shared__ int cur[GROWS];      // scatter cursor
    __shared__ int csr[CSR_CAP];    // row-sorted src ids (20 KB)

    const int t = threadIdx.x;
    const int bkt = blockIdx.x >> 1;        // parent 256-row bucket
    const int hsel = blockIdx.x & 1;        // which 128-row half
    const unsigned hbit = (unsigned)hsel << 7;
    const int beg = bkt * cap;
    int len = dcursor[bkt];
    if (len > cap) len = cap;
    const int end = beg + len;
    const int rowBase = bkt * BROWS + hsel * GROWS;

    const int wave = t >> 6;
    const int lane = t & 63;
    const int half = lane >> 5;     // which edge of the pair
    const int c    = lane & 31;     // column pair: cols 2c, 2c+1
    const __half2* __restrict__ m2 = (const __half2*)m;   // row stride 32
    const float2 bb = *(const float2*)(b + 2 * c);

    if (t < GROWS) cnt[t] = 0;
    __syncthreads();

    // ---- phase 1: per-row count of this half's edges
    for (int i = beg + t; i < end; i += 512) {
        unsigned p = pairs[i];
        if ((p & 128u) == hbit) atomicAdd(&cnt[p & 127u], 1);
    }
    __syncthreads();
    // ---- phase 2: inclusive scan (Hillis-Steele over 128)
    if (t < GROWS) rofs[t] = cnt[t];
    __syncthreads();
    #pragma unroll
    for (int d = 1; d < GROWS; d <<= 1) {
        int tv = (t < GROWS && t >= d) ? rofs[t - d] : 0;
        __syncthreads();
        if (t < GROWS) rofs[t] += tv;
        __syncthreads();
    }
    if (t < GROWS) cur[t] = rofs[t] - cnt[t];
    __syncthreads();
    const int tot = rofs[GROWS - 1];

    if (tot <= CSR_CAP) {
        // ---- phase 3: position-scatter src ids into LDS CSR (L2-hot re-read)
        for (int i = beg + t; i < end; i += 512) {
            unsigned p = pairs[i];
            if ((p & 128u) == hbit) {
                int pos = atomicAdd(&cur[p & 127u], 1);
                csr[pos] = (int)(p >> 8);
            }
        }
        __syncthreads();
        // ---- phase 4: dual-row gather + softmax (rA, rB = rA+8 interleaved)
        #pragma unroll 1
        for (int p8 = 0; p8 < GROWS / 16; ++p8) {
            const int rA = wave + 16 * p8;
            const int rB = rA + 8;
            const int eA = rofs[rA]; const int bAe = eA - cnt[rA];
            const int eB = rofs[rB]; const int bBe = eB - cnt[rB];
            float axA = 0.f, ayA = 0.f, axB = 0.f, ayB = 0.f;
            int iA = bAe, iB = bBe;
            while (iA + 16 <= eA && iB + 16 <= eB) {
                int sA[8], sB[8];
                #pragma unroll
                for (int k = 0; k < 8; ++k) sA[k] = csr[iA + 2 * k + half];
                #pragma unroll
                for (int k = 0; k < 8; ++k) sB[k] = csr[iB + 2 * k + half];
                float2 fA[8], fB[8];
                #pragma unroll
                for (int k = 0; k < 8; ++k)
                    fA[k] = __half22float2(m2[(unsigned)(sA[k] * (OUT_DIM / 2) + c)]);
                #pragma unroll
                for (int k = 0; k < 8; ++k)
                    fB[k] = __half22float2(m2[(unsigned)(sB[k] * (OUT_DIM / 2) + c)]);
                #pragma unroll
                for (int k = 0; k < 8; ++k) {
                    axA += fA[k].x; ayA += fA[k].y;
                    axB += fB[k].x; ayB += fB[k].y;
                }
                iA += 16; iB += 16;
            }
            for (; iA + 16 <= eA; iA += 16) {
                int s[8];
                #pragma unroll
                for (int k = 0; k < 8; ++k) s[k] = csr[iA + 2 * k + half];
                float2 f[8];
                #pragma unroll
                for (int k = 0; k < 8; ++k)
                    f[k] = __half22float2(m2[(unsigned)(s[k] * (OUT_DIM / 2) + c)]);
                #pragma unroll
                for (int k = 0; k < 8; ++k) { axA += f[k].x; ayA += f[k].y; }
            }
            for (int e = iA + half; e < eA; e += 2) {
                float2 f = __half22float2(m2[(unsigned)(csr[e] * (OUT_DIM / 2) + c)]);
                axA += f.x; ayA += f.y;
            }
            for (; iB + 16 <= eB; iB += 16) {
                int s[8];
                #pragma unroll
                for (int k = 0; k < 8; ++k) s[k] = csr[iB + 2 * k + half];
                float2 f[8];
                #pragma unroll
                for (int k = 0; k < 8; ++k)
                    f[k] = __half22float2(m2[(unsigned)(s[k] * (OUT_DIM / 2) + c)]);
                #pragma unroll
                for (int k = 0; k < 8; ++k) { axB += f[k].x; ayB += f[k].y; }
            }
            for (int e = iB + half; e < eB; e += 2) {
                float2 f = __half22float2(m2[(unsigned)(csr[e] * (OUT_DIM / 2) + c)]);
                axB += f.x; ayB += f.y;
            }
            #pragma unroll
            for (int which = 0; which < 2; ++which) {
                float ax = which ? axB : axA;
                float ay = which ? ayB : ayA;
                const int r = which ? rB : rA;
                const int row = rowBase + r;
                ax += __shfl_xor(ax, 32, 64);
                ay += __shfl_xor(ay, 32, 64);
                float nd = rsqrtf(fmaxf((float)cnt[r], 1.0f));
                float x0 = ax * nd + bb.x;
                float x1 = ay * nd + bb.y;
                float mx = fmaxf(x0, x1);
                #pragma unroll
                for (int o = 16; o > 0; o >>= 1) mx = fmaxf(mx, __shfl_xor(mx, o, 64));
                float ex0 = expf(x0 - mx), ex1 = expf(x1 - mx);
                float sm = ex0 + ex1;
                #pragma unroll
                for (int o = 16; o > 0; o >>= 1) sm += __shfl_xor(sm, o, 64);
                float ls = logf(sm);
                if (half == 0 && row < n_nodes)
                    *(float2*)(out + (size_t)row * OUT_DIM + 2 * c) =
                        make_float2(x0 - mx - ls, x1 - mx - ls);
            }
        }
    } else {
        // ---- slow fallback (pathological half-bucket > CSR_CAP; never on
        // this input): every lane scans the whole parent segment for its rows.
        for (int r = wave; r < GROWS; r += 8) {
            const int row = rowBase + r;
            if (row >= n_nodes) continue;
            const unsigned match = (unsigned)(hsel * GROWS + r);
            float ax = 0.f, ay = 0.f;
            for (int e = beg; e < end; ++e) {
                unsigned p = pairs[e];
                if ((p & 255u) == match) {
                    float2 f = __half22float2(m2[(unsigned)((p >> 8) * (OUT_DIM / 2) + c)]);
                    ax += f.x; ay += f.y;
                }
            }
            float nd = rsqrtf(fmaxf((float)cnt[r], 1.0f));
            float x0 = ax * nd + bb.x;
            float x1 = ay * nd + bb.y;
            float mx = fmaxf(x0, x1);
            #pragma unroll
            for (int o = 16; o > 0; o >>= 1) mx = fmaxf(mx, __shfl_xor(mx, o, 64));
            float ex0 = expf(x0 - mx), ex1 = expf(x1 - mx);
            float sm = ex0 + ex1;
            #pragma unroll
            for (int o = 16; o > 0; o >>= 1) sm += __shfl_xor(sm, o, 64);
            float ls = logf(sm);
            if (half == 0)
                *(float2*)(out + (size_t)row * OUT_DIM + 2 * c) =
                    make_float2(x0 - mx - ls, x1 - mx - ls);
        }
    }
}

// ---------------------------------------------------------------------------
static inline size_t align16(size_t x) { return (x + 15) & ~(size_t)15; }

extern "C" void kernel_launch(void* const* d_in, const int* in_sizes, int n_in,
                              void* d_out, int out_size, void* d_ws, size_t ws_size,
                              hipStream_t stream) {
    const float* h = (const float*)d_in[0];
    const float* W = (const float*)d_in[1];
    const float* b = (const float*)d_in[2];
    const int* edges = (const int*)d_in[3];

    const int out_dim = in_sizes[2];            // 64
    const int in_dim  = in_sizes[1] / out_dim;  // 256
    const int n_nodes = in_sizes[0] / in_dim;   // 100000
    const int n_edges = in_sizes[3] / 2;        // 3200000

    const int* src = edges;
    const int* dst = edges + n_edges;

    float* out = (float*)d_out;

    const int nb = (n_nodes + BROWS - 1) / BROWS;  // 391 buckets

    // fixed bucket segment capacity: mean + 25% + 1024, then 1K-align.
    const int epb = (n_edges + nb - 1) / nb;
    const int cap = (epb + (epb >> 2) + 1023 + 1023) & ~1023;

    // workspace carve-up (round-8 layout)
    char* ws = (char*)d_ws;
    size_t off = 0;
    int* out_deg     = (int*)(ws + off); off = align16(off + (size_t)n_nodes * 4);
    int* dcursor     = (int*)(ws + off); off = align16(off + (size_t)nb * 4);
    int* scursor     = (int*)(ws + off); off = align16(off + (size_t)nb * 4);
    __half* m        = (__half*)(ws + off); off = align16(off + (size_t)n_nodes * OUT_DIM * 2);
    unsigned* pairs  = (unsigned*)(ws + off); off = align16(off + (size_t)nb * cap * 4);
    // sbytes aliases m's storage (scatter writes, count_src reads, both
    // before gemm writes m; serial stream ordering). nb*cap (4 MB) <= 12.8 MB.
    unsigned char* sbytes = (unsigned char*)m;

    // zero both cursor arrays (contiguous)
    (void)hipMemsetAsync(dcursor, 0,
                         (size_t)((char*)(scursor + nb) - (char*)dcursor), stream);

    const int sc_blocks = (n_edges + SC_EDGES - 1) / SC_EDGES;

    scatter_pairs_kernel<<<sc_blocks, SC_THREADS, 0, stream>>>(
        src, dst, dcursor, scursor, pairs, sbytes, n_edges, nb, cap);
    count_src_kernel<<<nb, 256, 0, stream>>>(sbytes, scursor, out_deg, n_nodes, cap);

    gemm_kernel<<<(n_nodes + BM - 1) / BM, 256, 0, stream>>>(
        h, W, out_deg, m, n_nodes);

    bucket_gather_kernel<<<2 * nb, 512, 0, stream>>>(pairs, dcursor, m, b, out,
                                                     n_nodes, cap);
}